// Round 5
// baseline (9142.854 us; speedup 1.0000x reference)
//
#include <hip/hip_runtime.h>
#include <math.h>

#define SS 50
#define BB 2048
#define HH 128
#define DD 256
#define STEPS 49
#define NREF ((size_t)BB * SS * DD)   // 26,214,400 floats per ref tensor

__device__ __forceinline__ float sigmoidf_(float x) { return 1.0f / (1.0f + expf(-x)); }

// ---------------------------------------------------------------------------
// K0: init — x0 = tanh(fe @ W_first^T + b_first), q <- [h0_f | h0_b], c <- c0,
// unmasked-list = identity, lp = 0.   grid = B*D/256
// ---------------------------------------------------------------------------
__global__ __launch_bounds__(256) void k_init(
    const float* __restrict__ h0, const float* __restrict__ c0,
    const float* __restrict__ rk, const float* __restrict__ Wf,
    const float* __restrict__ bf,
    float* __restrict__ x, float* __restrict__ q, float* __restrict__ c,
    int* __restrict__ unm, float* __restrict__ lp)
{
    int idx = blockIdx.x * 256 + threadIdx.x;      // 0 .. B*D-1 == 0 .. 2*B*H-1
    int b = idx >> 8, d = idx & 255;
    float inv = 1.0f / rk[b];
    float t0 = 1.1f * Wf[2 * d] + inv * Wf[2 * d + 1];
    x[idx] = tanhf(t0 + bf[d]);
    q[idx] = (d < HH) ? h0[b * HH + d] : h0[BB * HH + b * HH + (d - HH)];
    c[idx] = c0[idx];
    if (idx < BB * 64) unm[idx] = idx & 63;        // list entries >=50 never read
    if (idx < BB) lp[idx] = 0.0f;
}

// ---------------------------------------------------------------------------
// P1: refX[b][s][d] = sum_e WX[d][e] * enc[s][b][e]  for X in {g, p, q}
// tile 64(M) x 256(N), 256 threads, acc 4x16.  grid (1600, 1, 2 or 3)
// ---------------------------------------------------------------------------
__global__ __launch_bounds__(256) void k_refdot(
    const float* __restrict__ enc, const float* __restrict__ Wg,
    const float* __restrict__ Wp, const float* __restrict__ Wqq,
    float* __restrict__ refg, float* __restrict__ refp, float* __restrict__ refq)
{
    const float* W = (blockIdx.z == 0) ? Wg : (blockIdx.z == 1) ? Wp : Wqq;
    float* out = (blockIdx.z == 0) ? refg : (blockIdx.z == 1) ? refp : refq;
    __shared__ float As[16][68];
    __shared__ float Ws[16][264];
    int t = threadIdx.x;
    int m0 = blockIdx.x * 64;
    int rr = t >> 2, kk = (t & 3) << 2;
    int n = m0 + rr;
    int ab = n / SS, as = n - ab * SS;
    const float* arow = enc + ((size_t)as * BB + ab) * DD + kk;
    const float* wrow = W + (size_t)t * DD;
    int tm = (t & 15) << 2;
    int tn = (t >> 4) << 4;
    float acc[4][16];
#pragma unroll
    for (int i = 0; i < 4; i++)
#pragma unroll
        for (int j = 0; j < 16; j++) acc[i][j] = 0.0f;

    for (int k0 = 0; k0 < DD; k0 += 16) {
        float4 av = *(const float4*)(arow + k0);
        float4 w0 = *(const float4*)(wrow + k0);
        float4 w1 = *(const float4*)(wrow + k0 + 4);
        float4 w2 = *(const float4*)(wrow + k0 + 8);
        float4 w3 = *(const float4*)(wrow + k0 + 12);
        __syncthreads();
        As[kk + 0][rr] = av.x; As[kk + 1][rr] = av.y;
        As[kk + 2][rr] = av.z; As[kk + 3][rr] = av.w;
        Ws[0][t] = w0.x;  Ws[1][t] = w0.y;  Ws[2][t] = w0.z;  Ws[3][t] = w0.w;
        Ws[4][t] = w1.x;  Ws[5][t] = w1.y;  Ws[6][t] = w1.z;  Ws[7][t] = w1.w;
        Ws[8][t] = w2.x;  Ws[9][t] = w2.y;  Ws[10][t] = w2.z; Ws[11][t] = w2.w;
        Ws[12][t] = w3.x; Ws[13][t] = w3.y; Ws[14][t] = w3.z; Ws[15][t] = w3.w;
        __syncthreads();
#pragma unroll
        for (int k = 0; k < 16; k++) {
            float4 a = *(const float4*)&As[k][tm];
            float aa[4] = {a.x, a.y, a.z, a.w};
#pragma unroll
            for (int jj = 0; jj < 4; jj++) {
                float4 w = *(const float4*)&Ws[k][tn + (jj << 2)];
                float ww[4] = {w.x, w.y, w.z, w.w};
#pragma unroll
                for (int i = 0; i < 4; i++)
#pragma unroll
                    for (int cj = 0; cj < 4; cj++)
                        acc[i][jj * 4 + cj] = fmaf(aa[i], ww[cj], acc[i][jj * 4 + cj]);
            }
        }
    }
#pragma unroll
    for (int i = 0; i < 4; i++) {
        float* orow = out + (size_t)(m0 + tm + i) * DD + tn;
#pragma unroll
        for (int jj = 0; jj < 4; jj++) {
            float4 o = make_float4(acc[i][jj * 4], acc[i][jj * 4 + 1],
                                   acc[i][jj * 4 + 2], acc[i][jj * 4 + 3]);
            *(float4*)(orow + (jj << 2)) = o;
        }
    }
}

// ---------------------------------------------------------------------------
// K1: fused gates GEMM + LSTM pointwise.
// block = 32 batch rows x 64 h-cols x 1 dir; computes all 4 gates, applies
// sigmoid/tanh, writes qout and c.  grid (64, 2, 2), 256 thr.
// Reads qin (prev h), writes qout (ping-pong; never the same buffer).
// ---------------------------------------------------------------------------
__global__ __launch_bounds__(256) void k_gates2(
    const float* __restrict__ x, const float* __restrict__ qin,
    const float* __restrict__ Wih_f, const float* __restrict__ Whh_f,
    const float* __restrict__ bih_f, const float* __restrict__ bhh_f,
    const float* __restrict__ Wih_b, const float* __restrict__ Whh_b,
    const float* __restrict__ bih_b, const float* __restrict__ bhh_b,
    float* __restrict__ qout, float* __restrict__ c)
{
    int z = blockIdx.z;
    const float* Wih = z ? Wih_b : Wih_f;
    const float* Whh = z ? Whh_b : Whh_f;
    const float* bih = z ? bih_b : bih_f;
    const float* bhh = z ? bhh_b : bhh_f;
    int m0 = blockIdx.x * 32;
    int hc0 = blockIdx.y * 64;
    int t = threadIdx.x;
    int mb4 = (t >> 5) << 2;        // 0,4,..,28 : first of 4 batch rows
    int hp2 = (t & 31) << 1;        // 0,2,..,62 : first of 2 h-cols (local)
    __shared__ float As[16][33];
    __shared__ float Ws[16][258];
    float acc[4][4][2] = {};        // [m][gate][col]

    for (int k0 = 0; k0 < 384; k0 += 16) {
        float4 av;
        int am = t >> 2, ak = (t & 3) << 2;
        if (t < 128) {
            if (k0 < 256)
                av = *(const float4*)(x + (size_t)(m0 + am) * DD + k0 + ak);
            else
                av = *(const float4*)(qin + (size_t)(m0 + am) * DD + (z << 7) + (k0 - 256) + ak);
        }
        int g = t >> 6, hc = t & 63;
        int r = g * 128 + hc0 + hc;
        float4 w0, w1, w2, w3;
        if (k0 < 256) {
            const float* wr = Wih + (size_t)r * DD + k0;
            w0 = *(const float4*)(wr);     w1 = *(const float4*)(wr + 4);
            w2 = *(const float4*)(wr + 8); w3 = *(const float4*)(wr + 12);
        } else {
            const float* wr = Whh + (size_t)r * HH + (k0 - 256);
            w0 = *(const float4*)(wr);     w1 = *(const float4*)(wr + 4);
            w2 = *(const float4*)(wr + 8); w3 = *(const float4*)(wr + 12);
        }
        __syncthreads();
        if (t < 128) {
            As[ak + 0][am] = av.x; As[ak + 1][am] = av.y;
            As[ak + 2][am] = av.z; As[ak + 3][am] = av.w;
        }
        Ws[0][t] = w0.x;  Ws[1][t] = w0.y;  Ws[2][t] = w0.z;  Ws[3][t] = w0.w;
        Ws[4][t] = w1.x;  Ws[5][t] = w1.y;  Ws[6][t] = w1.z;  Ws[7][t] = w1.w;
        Ws[8][t] = w2.x;  Ws[9][t] = w2.y;  Ws[10][t] = w2.z; Ws[11][t] = w2.w;
        Ws[12][t] = w3.x; Ws[13][t] = w3.y; Ws[14][t] = w3.z; Ws[15][t] = w3.w;
        __syncthreads();
#pragma unroll
        for (int k = 0; k < 16; ++k) {
            float a0 = As[k][mb4 + 0];
            float a1 = As[k][mb4 + 1];
            float a2 = As[k][mb4 + 2];
            float a3 = As[k][mb4 + 3];
#pragma unroll
            for (int g2 = 0; g2 < 4; ++g2) {
                float2 wv = *(const float2*)&Ws[k][(g2 << 6) + hp2];
                acc[0][g2][0] = fmaf(a0, wv.x, acc[0][g2][0]);
                acc[0][g2][1] = fmaf(a0, wv.y, acc[0][g2][1]);
                acc[1][g2][0] = fmaf(a1, wv.x, acc[1][g2][0]);
                acc[1][g2][1] = fmaf(a1, wv.y, acc[1][g2][1]);
                acc[2][g2][0] = fmaf(a2, wv.x, acc[2][g2][0]);
                acc[2][g2][1] = fmaf(a2, wv.y, acc[2][g2][1]);
                acc[3][g2][0] = fmaf(a3, wv.x, acc[3][g2][0]);
                acc[3][g2][1] = fmaf(a3, wv.y, acc[3][g2][1]);
            }
        }
    }
#pragma unroll
    for (int i = 0; i < 4; ++i) {
#pragma unroll
        for (int cc = 0; cc < 2; ++cc) {
            int b = m0 + mb4 + i;
            int h = hc0 + hp2 + cc;
            float gi = acc[i][0][cc] + bih[h]       + bhh[h];
            float gf = acc[i][1][cc] + bih[128 + h] + bhh[128 + h];
            float gg = acc[i][2][cc] + bih[256 + h] + bhh[256 + h];
            float go = acc[i][3][cc] + bih[384 + h] + bhh[384 + h];
            size_t cidx = (size_t)z * BB * HH + (size_t)b * HH + h;
            float c2 = sigmoidf_(gf) * c[cidx] + sigmoidf_(gi) * tanhf(gg);
            c[cidx] = c2;
            qout[(size_t)b * DD + (z << 7) + h] = sigmoidf_(go) * tanhf(c2);
        }
    }
}

// ---------------------------------------------------------------------------
// K2: fused attention: qW proj -> u_g -> softmax -> gW (refq or enc+Wq) ->
// u_p -> argmax/lp/swap-remove -> gather next x.  grid (BB), 256 thr.
// ---------------------------------------------------------------------------
__global__ __launch_bounds__(256) void k_attn(
    const float* __restrict__ refg, const float* __restrict__ refp,
    const float* __restrict__ refq, const float* __restrict__ q,
    const float* __restrict__ Wqg, const float* __restrict__ vg,
    const float* __restrict__ Wqp, const float* __restrict__ vp,
    const float* __restrict__ enc, int* __restrict__ unm,
    float* __restrict__ lp, float* __restrict__ x,
    float* __restrict__ outp, int step, int cnt)
{
    int b = blockIdx.x, t = threadIdx.x;
    int wave = t >> 6, lane = t & 63;
    __shared__ float qsh[DD];
    __shared__ float qw[DD];
    __shared__ float gw[DD];
    __shared__ float uu[64];
    __shared__ float aa[64];
    __shared__ int sl[64];
    __shared__ int ssel;
    if (t < cnt) sl[t] = unm[b * 64 + t];
    qsh[t] = q[(size_t)b * DD + t];
    __syncthreads();
    // phase 0: qw[t] = q[b] . Wqg[t]
    {
        const float* wr = Wqg + (size_t)t * DD;
        float s0 = 0, s1 = 0, s2 = 0, s3 = 0;
        for (int e = 0; e < DD; e += 4) {
            float4 w = *(const float4*)(wr + e);
            float4 qv = *(const float4*)(qsh + e);
            s0 = fmaf(w.x, qv.x, s0); s1 = fmaf(w.y, qv.y, s1);
            s2 = fmaf(w.z, qv.z, s2); s3 = fmaf(w.w, qv.w, s3);
        }
        qw[t] = (s0 + s1) + (s2 + s3);
    }
    __syncthreads();
    // phase 1: u_g over active rows
    int d0 = lane << 2;
    {
        float4 vvg = *(const float4*)(vg + d0);
        float4 qw4 = *(const float4*)(&qw[d0]);
        for (int li = wave; li < cnt; li += 4) {
            int s = sl[li];
            float4 r = *(const float4*)(refg + ((size_t)b * SS + s) * DD + d0);
            float sum = vvg.x * tanhf(r.x + qw4.x) + vvg.y * tanhf(r.y + qw4.y) +
                        vvg.z * tanhf(r.z + qw4.z) + vvg.w * tanhf(r.w + qw4.w);
#pragma unroll
            for (int off = 32; off; off >>= 1) sum += __shfl_xor(sum, off);
            if (lane == 0) uu[li] = sum;
        }
    }
    __syncthreads();
    // phase 2: softmax over active rows
    if (t < 64) {
        float logit = (t < cnt) ? uu[t] : -__builtin_inff();
        float m = logit;
#pragma unroll
        for (int off = 32; off; off >>= 1) m = fmaxf(m, __shfl_xor(m, off));
        float e = expf(logit - m);
        float ssum = e;
#pragma unroll
        for (int off = 32; off; off >>= 1) ssum += __shfl_xor(ssum, off);
        if (t < cnt) aa[t] = e / ssum;
    }
    __syncthreads();
    // phase 3: gw
    if (refq) {
        float accg = 0.0f;
        for (int li = 0; li < cnt; ++li)
            accg = fmaf(aa[li], refq[((size_t)b * SS + sl[li]) * DD + t], accg);
        gw[t] = accg;
    } else {
        float accl = 0.0f;
        for (int li = 0; li < cnt; ++li)
            accl = fmaf(aa[li], enc[((size_t)sl[li] * BB + b) * DD + t], accl);
        qsh[t] = accl;                 // reuse qsh as g_l
        __syncthreads();
        const float* wr = Wqp + (size_t)t * DD;
        float s0 = 0, s1 = 0, s2 = 0, s3 = 0;
        for (int e = 0; e < DD; e += 4) {
            float4 w = *(const float4*)(wr + e);
            float4 gv = *(const float4*)(qsh + e);
            s0 = fmaf(w.x, gv.x, s0); s1 = fmaf(w.y, gv.y, s1);
            s2 = fmaf(w.z, gv.z, s2); s3 = fmaf(w.w, gv.w, s3);
        }
        gw[t] = (s0 + s1) + (s2 + s3);
    }
    __syncthreads();
    // phase 4: u_p over active rows
    {
        float4 vvp = *(const float4*)(vp + d0);
        float4 gw4 = *(const float4*)(&gw[d0]);
        for (int li = wave; li < cnt; li += 4) {
            int s = sl[li];
            float4 r = *(const float4*)(refp + ((size_t)b * SS + s) * DD + d0);
            float sum = vvp.x * tanhf(r.x + gw4.x) + vvp.y * tanhf(r.y + gw4.y) +
                        vvp.z * tanhf(r.z + gw4.z) + vvp.w * tanhf(r.w + gw4.w);
#pragma unroll
            for (int off = 32; off; off >>= 1) sum += __shfl_xor(sum, off);
            if (lane == 0) uu[li] = sum;
        }
    }
    __syncthreads();
    // phase 5: argmax (min-s tie-break), lp, outputs, swap-remove
    if (t < 64) {
        float logit = (t < cnt) ? uu[t] : -__builtin_inff();
        int skey = (t < cnt) ? (sl[t] * 64 + t) : (1 << 30);
        float m = logit;
#pragma unroll
        for (int off = 32; off; off >>= 1) m = fmaxf(m, __shfl_xor(m, off));
        int cand = (logit == m) ? skey : (1 << 30);
#pragma unroll
        for (int off = 32; off; off >>= 1) cand = min(cand, __shfl_xor(cand, off));
        float e = expf(logit - m);
        float se = e;
#pragma unroll
        for (int off = 32; off; off >>= 1) se += __shfl_xor(se, off);
        if (t == 0) {
            int s_sel = cand >> 6, posl = cand & 63;
            float lpn = lp[b] - logf(se);
            lp[b] = lpn;
            outp[(size_t)b * STEPS + step] = (float)s_sel;
            if (step == STEPS - 1) outp[(size_t)BB * STEPS + b] = lpn;
            unm[b * 64 + posl] = sl[cnt - 1];   // swap-remove
            ssel = s_sel;
        }
    }
    __syncthreads();
    x[(size_t)b * DD + t] = enc[((size_t)ssel * BB + b) * DD + t];
}

// ---------------------------------------------------------------------------
extern "C" void kernel_launch(void* const* d_in, const int* in_sizes, int n_in,
                              void* d_out, int out_size, void* d_ws, size_t ws_size,
                              hipStream_t stream) {
    const float* enc    = (const float*)d_in[0];
    const float* h0     = (const float*)d_in[1];
    const float* c0     = (const float*)d_in[2];
    const float* rk     = (const float*)d_in[3];
    const float* Wfirst = (const float*)d_in[4];
    const float* bfirst = (const float*)d_in[5];
    const float* Wih_f  = (const float*)d_in[6];
    const float* Whh_f  = (const float*)d_in[7];
    const float* bih_f  = (const float*)d_in[8];
    const float* bhh_f  = (const float*)d_in[9];
    const float* Wih_b  = (const float*)d_in[10];
    const float* Whh_b  = (const float*)d_in[11];
    const float* bih_b  = (const float*)d_in[12];
    const float* bhh_b  = (const float*)d_in[13];
    const float* Wref_g = (const float*)d_in[14];
    const float* Wq_g   = (const float*)d_in[15];
    const float* vg     = (const float*)d_in[16];
    const float* Wref   = (const float*)d_in[17];
    const float* Wq     = (const float*)d_in[18];
    const float* v      = (const float*)d_in[19];
    float* out = (float*)d_out;

    float* ws   = (float*)d_ws;
    float* refg = ws;
    float* refp = refg + NREF;
    float* x    = refp + NREF;
    float* qA   = x + (size_t)BB * DD;
    float* qB   = qA + (size_t)BB * DD;
    float* c    = qB + (size_t)BB * DD;
    float* lp   = c + (size_t)2 * BB * HH;
    int*   unm  = (int*)(lp + BB);
    float* refq = (float*)(unm + (size_t)BB * 64);   // optional tail

    size_t need_refq = ((size_t)(refq - ws) + NREF) * sizeof(float);
    bool useRefq = ws_size >= need_refq;
    const float* refq_arg = useRefq ? refq : nullptr;

    k_init<<<dim3(BB * DD / 256), dim3(256), 0, stream>>>(h0, c0, rk, Wfirst,
                                                          bfirst, x, qA, c, unm, lp);
    k_refdot<<<dim3(BB * SS / 64, 1, useRefq ? 3 : 2), dim3(256), 0, stream>>>(
        enc, Wref_g, Wref, Wq, refg, refp, refq);
    for (int step = 0; step < STEPS; ++step) {
        int cnt = SS - step;
        float* qin  = (step & 1) ? qB : qA;
        float* qout = (step & 1) ? qA : qB;
        k_gates2<<<dim3(64, 2, 2), dim3(256), 0, stream>>>(
            x, qin, Wih_f, Whh_f, bih_f, bhh_f, Wih_b, Whh_b, bih_b, bhh_b, qout, c);
        k_attn<<<dim3(BB), dim3(256), 0, stream>>>(
            refg, refp, refq_arg, qout, Wq_g, vg, Wq, v, enc, unm, lp, x, out,
            step, cnt);
    }
}

// Round 8
// 4650.215 us; speedup vs baseline: 1.9661x; 1.9661x over previous
//
#include <hip/hip_runtime.h>
#include <math.h>

#define SS 50
#define BB 2048
#define HH 128
#define DD 256
#define STEPS 49
#define NREF ((size_t)BB * SS * DD)   // 26,214,400 floats per ref tensor

__device__ __forceinline__ float sigmoidf_(float x) { return 1.0f / (1.0f + expf(-x)); }

// ---------------------------------------------------------------------------
// K0: init — x0 = tanh(fe @ W_first^T + b_first), q <- [h0_f | h0_b], c <- c0,
// unmasked-list = identity, lp = 0.   grid = B*D/256
// ---------------------------------------------------------------------------
__global__ __launch_bounds__(256) void k_init(
    const float* __restrict__ h0, const float* __restrict__ c0,
    const float* __restrict__ rk, const float* __restrict__ Wf,
    const float* __restrict__ bf,
    float* __restrict__ x, float* __restrict__ q, float* __restrict__ c,
    int* __restrict__ unm, float* __restrict__ lp)
{
    int idx = blockIdx.x * 256 + threadIdx.x;      // 0 .. B*D-1 == 0 .. 2*B*H-1
    int b = idx >> 8, d = idx & 255;
    float inv = 1.0f / rk[b];
    float t0 = 1.1f * Wf[2 * d] + inv * Wf[2 * d + 1];
    x[idx] = tanhf(t0 + bf[d]);
    q[idx] = (d < HH) ? h0[b * HH + d] : h0[BB * HH + b * HH + (d - HH)];
    c[idx] = c0[idx];
    if (idx < BB * 64) unm[idx] = idx & 63;        // list entries >=50 never read
    if (idx < BB) lp[idx] = 0.0f;
}

// ---------------------------------------------------------------------------
// P1: refX[b][s][d] = sum_e WX[d][e] * enc[s][b][e]  for X in {g, p, q}
// tile 128(M) x 256(N), 256 threads, acc 8x16 (lo/hi 64-row halves).
// grid (800, 1, 2 or 3)
// ---------------------------------------------------------------------------
__global__ __launch_bounds__(256) void k_refdot(
    const float* __restrict__ enc, const float* __restrict__ Wg,
    const float* __restrict__ Wp, const float* __restrict__ Wqq,
    float* __restrict__ refg, float* __restrict__ refp, float* __restrict__ refq)
{
    const float* W = (blockIdx.z == 0) ? Wg : (blockIdx.z == 1) ? Wp : Wqq;
    float* out = (blockIdx.z == 0) ? refg : (blockIdx.z == 1) ? refp : refq;
    __shared__ float As[16][132];   // 128 rows (lo 0..63, hi 64..127) + pad
    __shared__ float Ws[16][264];
    int t = threadIdx.x;
    int m0 = blockIdx.x * 128;
    int rr = t >> 2, kk = (t & 3) << 2;
    int n0 = m0 + rr, n1 = m0 + 64 + rr;
    int ab0 = n0 / SS, as0 = n0 - ab0 * SS;
    int ab1 = n1 / SS, as1 = n1 - ab1 * SS;
    const float* arow0 = enc + ((size_t)as0 * BB + ab0) * DD + kk;
    const float* arow1 = enc + ((size_t)as1 * BB + ab1) * DD + kk;
    const float* wrow = W + (size_t)t * DD;
    int tm = (t & 15) << 2;        // 4 lo rows + 4 hi rows per thread
    int tn = (t >> 4) << 4;        // 16 cols
    float acc[8][16];
#pragma unroll
    for (int i = 0; i < 8; i++)
#pragma unroll
        for (int j = 0; j < 16; j++) acc[i][j] = 0.0f;

    for (int k0 = 0; k0 < DD; k0 += 16) {
        float4 a0 = *(const float4*)(arow0 + k0);
        float4 a1 = *(const float4*)(arow1 + k0);
        float4 w0 = *(const float4*)(wrow + k0);
        float4 w1 = *(const float4*)(wrow + k0 + 4);
        float4 w2 = *(const float4*)(wrow + k0 + 8);
        float4 w3 = *(const float4*)(wrow + k0 + 12);
        __syncthreads();
        As[kk + 0][rr] = a0.x; As[kk + 1][rr] = a0.y;
        As[kk + 2][rr] = a0.z; As[kk + 3][rr] = a0.w;
        As[kk + 0][64 + rr] = a1.x; As[kk + 1][64 + rr] = a1.y;
        As[kk + 2][64 + rr] = a1.z; As[kk + 3][64 + rr] = a1.w;
        Ws[0][t] = w0.x;  Ws[1][t] = w0.y;  Ws[2][t] = w0.z;  Ws[3][t] = w0.w;
        Ws[4][t] = w1.x;  Ws[5][t] = w1.y;  Ws[6][t] = w1.z;  Ws[7][t] = w1.w;
        Ws[8][t] = w2.x;  Ws[9][t] = w2.y;  Ws[10][t] = w2.z; Ws[11][t] = w2.w;
        Ws[12][t] = w3.x; Ws[13][t] = w3.y; Ws[14][t] = w3.z; Ws[15][t] = w3.w;
        __syncthreads();
#pragma unroll
        for (int k = 0; k < 16; k++) {
            float4 alo = *(const float4*)&As[k][tm];
            float4 ahi = *(const float4*)&As[k][64 + tm];
            float aa[8] = {alo.x, alo.y, alo.z, alo.w, ahi.x, ahi.y, ahi.z, ahi.w};
#pragma unroll
            for (int jj = 0; jj < 4; jj++) {
                float4 w = *(const float4*)&Ws[k][tn + (jj << 2)];
                float ww[4] = {w.x, w.y, w.z, w.w};
#pragma unroll
                for (int i = 0; i < 8; i++)
#pragma unroll
                    for (int cj = 0; cj < 4; cj++)
                        acc[i][jj * 4 + cj] = fmaf(aa[i], ww[cj], acc[i][jj * 4 + cj]);
            }
        }
    }
#pragma unroll
    for (int i = 0; i < 8; i++) {
        int row = (i < 4) ? (m0 + tm + i) : (m0 + 64 + tm + (i - 4));
        float* orow = out + (size_t)row * DD + tn;
#pragma unroll
        for (int jj = 0; jj < 4; jj++) {
            float4 o = make_float4(acc[i][jj * 4], acc[i][jj * 4 + 1],
                                   acc[i][jj * 4 + 2], acc[i][jj * 4 + 3]);
            *(float4*)(orow + (jj << 2)) = o;
        }
    }
}

// ---------------------------------------------------------------------------
// K1: gates GEMM.  M=2048, N=512 (per dir), K=384. tile 64x64. grid (32,8,2)
// (exact R4 kernel — measured-good)
// ---------------------------------------------------------------------------
__global__ __launch_bounds__(256) void k_gates(
    const float* __restrict__ x, const float* __restrict__ q,
    const float* __restrict__ Wih_f, const float* __restrict__ Whh_f,
    const float* __restrict__ bih_f, const float* __restrict__ bhh_f,
    const float* __restrict__ Wih_b, const float* __restrict__ Whh_b,
    const float* __restrict__ bih_b, const float* __restrict__ bhh_b,
    float* __restrict__ gates)
{
    int z = blockIdx.z;
    const float* Wih = z ? Wih_b : Wih_f;
    const float* Whh = z ? Whh_b : Whh_f;
    const float* bih = z ? bih_b : bih_f;
    const float* bhh = z ? bhh_b : bhh_f;
    __shared__ float As[16][68];
    __shared__ float Ws[16][68];
    int t = threadIdx.x;
    int m0 = blockIdx.x * 64, n0 = blockIdx.y * 64;
    int rr = t >> 2, kk = (t & 3) << 2;
    int tm = (t & 15) << 2, tn = (t >> 4) << 2;
    float acc[4][4] = {};
    for (int k0 = 0; k0 < 384; k0 += 16) {
        float4 av, wv;
        if (k0 < 256) {
            av = *(const float4*)(x + (size_t)(m0 + rr) * DD + k0 + kk);
            wv = *(const float4*)(Wih + (size_t)(n0 + rr) * DD + k0 + kk);
        } else {
            av = *(const float4*)(q + (size_t)(m0 + rr) * DD + (z << 7) + (k0 - 256) + kk);
            wv = *(const float4*)(Whh + (size_t)(n0 + rr) * HH + (k0 - 256) + kk);
        }
        __syncthreads();
        As[kk + 0][rr] = av.x; As[kk + 1][rr] = av.y;
        As[kk + 2][rr] = av.z; As[kk + 3][rr] = av.w;
        Ws[kk + 0][rr] = wv.x; Ws[kk + 1][rr] = wv.y;
        Ws[kk + 2][rr] = wv.z; Ws[kk + 3][rr] = wv.w;
        __syncthreads();
#pragma unroll
        for (int k = 0; k < 16; k++) {
            float4 a = *(const float4*)&As[k][tm];
            float4 w = *(const float4*)&Ws[k][tn];
            float aa[4] = {a.x, a.y, a.z, a.w};
            float ww[4] = {w.x, w.y, w.z, w.w};
#pragma unroll
            for (int i = 0; i < 4; i++)
#pragma unroll
                for (int j = 0; j < 4; j++)
                    acc[i][j] = fmaf(aa[i], ww[j], acc[i][j]);
        }
    }
#pragma unroll
    for (int i = 0; i < 4; i++) {
        int col = n0 + tn;
        float4 o;
        o.x = acc[i][0] + bih[col + 0] + bhh[col + 0];
        o.y = acc[i][1] + bih[col + 1] + bhh[col + 1];
        o.z = acc[i][2] + bih[col + 2] + bhh[col + 2];
        o.w = acc[i][3] + bih[col + 3] + bhh[col + 3];
        *(float4*)(gates + (size_t)(m0 + tm + i) * 1024 + (z << 9) + col) = o;
    }
}

// ---------------------------------------------------------------------------
// K2: LSTM pointwise.  idx over 2*B*H.  grid 2048   (exact R4 kernel)
// ---------------------------------------------------------------------------
__global__ __launch_bounds__(256) void k_lstm_pw(
    const float* __restrict__ gates, float* __restrict__ q, float* __restrict__ c)
{
    int idx = blockIdx.x * 256 + threadIdx.x;   // 0 .. 2*B*H-1
    int z = idx >> 18;                          // B*H = 2^18
    int r = idx & (BB * HH - 1);
    int b = r >> 7, hh = r & 127;
    const float* gb = gates + (size_t)b * 1024 + (z << 9);
    float ig = sigmoidf_(gb[hh]);
    float fg = sigmoidf_(gb[128 + hh]);
    float gg = tanhf(gb[256 + hh]);
    float og = sigmoidf_(gb[384 + hh]);
    float c2 = fg * c[idx] + ig * gg;
    c[idx] = c2;
    q[(size_t)b * DD + (z << 7) + hh] = og * tanhf(c2);
}

// ---------------------------------------------------------------------------
// K3: out[b][d] = sum_e A[b][e] * W[d][e]   (M=2048,N=256,K=256). grid (32,4)
// (exact R4 kernel)
// ---------------------------------------------------------------------------
__global__ __launch_bounds__(256) void k_proj(
    const float* __restrict__ A, const float* __restrict__ W, float* __restrict__ out)
{
    __shared__ float As[16][68];
    __shared__ float Ws[16][68];
    int t = threadIdx.x;
    int m0 = blockIdx.x * 64, n0 = blockIdx.y * 64;
    int rr = t >> 2, kk = (t & 3) << 2;
    int tm = (t & 15) << 2, tn = (t >> 4) << 2;
    const float* arow = A + (size_t)(m0 + rr) * DD + kk;
    const float* wrow = W + (size_t)(n0 + rr) * DD + kk;
    float acc[4][4] = {};
    for (int k0 = 0; k0 < DD; k0 += 16) {
        float4 av = *(const float4*)(arow + k0);
        float4 wv = *(const float4*)(wrow + k0);
        __syncthreads();
        As[kk + 0][rr] = av.x; As[kk + 1][rr] = av.y;
        As[kk + 2][rr] = av.z; As[kk + 3][rr] = av.w;
        Ws[kk + 0][rr] = wv.x; Ws[kk + 1][rr] = wv.y;
        Ws[kk + 2][rr] = wv.z; Ws[kk + 3][rr] = wv.w;
        __syncthreads();
#pragma unroll
        for (int k = 0; k < 16; k++) {
            float4 a = *(const float4*)&As[k][tm];
            float4 w = *(const float4*)&Ws[k][tn];
            float aa[4] = {a.x, a.y, a.z, a.w};
            float ww[4] = {w.x, w.y, w.z, w.w};
#pragma unroll
            for (int i = 0; i < 4; i++)
#pragma unroll
                for (int j = 0; j < 4; j++)
                    acc[i][j] = fmaf(aa[i], ww[j], acc[i][j]);
        }
    }
#pragma unroll
    for (int i = 0; i < 4; i++) {
        float4 o = make_float4(acc[i][0], acc[i][1], acc[i][2], acc[i][3]);
        *(float4*)(out + (size_t)(m0 + tm + i) * DD + n0 + tn) = o;
    }
}

// ---------------------------------------------------------------------------
// K4: merged glimpse+pointer (refq path). qW from k_proj (tiled GEMM).
// u_g -> softmax -> gw(refq) -> u_p -> argmax/lp/swap-remove -> gather x.
// grid (BB), 256 thr.  (concatenation of R4's k_glimpse + k_pointer bodies;
// a[] handoff moved to LDS — no access-pattern changes)
// ---------------------------------------------------------------------------
__global__ __launch_bounds__(256) void k_attn2(
    const float* __restrict__ refg, const float* __restrict__ refp,
    const float* __restrict__ refq, const float* __restrict__ qW,
    const float* __restrict__ vg, const float* __restrict__ vp,
    const float* __restrict__ enc, int* __restrict__ unm,
    float* __restrict__ lp, float* __restrict__ x,
    float* __restrict__ outp, int step, int cnt)
{
    int b = blockIdx.x, t = threadIdx.x;
    int wave = t >> 6, lane = t & 63;
    __shared__ float uu[64];
    __shared__ float aa[64];
    __shared__ float gw[DD];
    __shared__ int sl[64];
    __shared__ int ssel;
    if (t < cnt) sl[t] = unm[b * 64 + t];
    __syncthreads();
    int d0 = lane << 2;
    // u_g over active rows
    {
        float4 vvg = *(const float4*)(vg + d0);
        float4 qw4 = *(const float4*)(qW + (size_t)b * DD + d0);
        for (int li = wave; li < cnt; li += 4) {
            int s = sl[li];
            float4 r = *(const float4*)(refg + ((size_t)b * SS + s) * DD + d0);
            float sum = vvg.x * tanhf(r.x + qw4.x) + vvg.y * tanhf(r.y + qw4.y) +
                        vvg.z * tanhf(r.z + qw4.z) + vvg.w * tanhf(r.w + qw4.w);
#pragma unroll
            for (int off = 32; off; off >>= 1) sum += __shfl_xor(sum, off);
            if (lane == 0) uu[li] = sum;
        }
    }
    __syncthreads();
    // softmax over active rows
    if (t < 64) {
        float logit = (t < cnt) ? uu[t] : -__builtin_inff();
        float m = logit;
#pragma unroll
        for (int off = 32; off; off >>= 1) m = fmaxf(m, __shfl_xor(m, off));
        float e = expf(logit - m);
        float ssum = e;
#pragma unroll
        for (int off = 32; off; off >>= 1) ssum += __shfl_xor(ssum, off);
        if (t < cnt) aa[t] = e / ssum;
    }
    __syncthreads();
    // gw[t] = sum_li aa[li] * refq[b][sl[li]][t]
    {
        float accg = 0.0f;
        for (int li = 0; li < cnt; ++li)
            accg = fmaf(aa[li], refq[((size_t)b * SS + sl[li]) * DD + t], accg);
        gw[t] = accg;
    }
    __syncthreads();
    // u_p over active rows
    {
        float4 vvp = *(const float4*)(vp + d0);
        float4 gw4 = *(const float4*)(&gw[d0]);
        for (int li = wave; li < cnt; li += 4) {
            int s = sl[li];
            float4 r = *(const float4*)(refp + ((size_t)b * SS + s) * DD + d0);
            float sum = vvp.x * tanhf(r.x + gw4.x) + vvp.y * tanhf(r.y + gw4.y) +
                        vvp.z * tanhf(r.z + gw4.z) + vvp.w * tanhf(r.w + gw4.w);
#pragma unroll
            for (int off = 32; off; off >>= 1) sum += __shfl_xor(sum, off);
            if (lane == 0) uu[li] = sum;
        }
    }
    __syncthreads();
    // argmax (min-s tie-break), lp, outputs, swap-remove
    if (t < 64) {
        float logit = (t < cnt) ? uu[t] : -__builtin_inff();
        int skey = (t < cnt) ? (sl[t] * 64 + t) : (1 << 30);
        float m = logit;
#pragma unroll
        for (int off = 32; off; off >>= 1) m = fmaxf(m, __shfl_xor(m, off));
        int cand = (logit == m) ? skey : (1 << 30);
#pragma unroll
        for (int off = 32; off; off >>= 1) cand = min(cand, __shfl_xor(cand, off));
        float e = expf(logit - m);
        float se = e;
#pragma unroll
        for (int off = 32; off; off >>= 1) se += __shfl_xor(se, off);
        if (t == 0) {
            int s_sel = cand >> 6, posl = cand & 63;
            float lpn = lp[b] - logf(se);
            lp[b] = lpn;
            outp[(size_t)b * STEPS + step] = (float)s_sel;
            if (step == STEPS - 1) outp[(size_t)BB * STEPS + b] = lpn;
            unm[b * 64 + posl] = sl[cnt - 1];   // swap-remove
            ssel = s_sel;
        }
    }
    __syncthreads();
    x[(size_t)b * DD + t] = enc[((size_t)ssel * BB + b) * DD + t];
}

// ---------------------------------------------------------------------------
// Fallback kernels (no-refq path) — exact R4 k_glimpse / k_pointer
// ---------------------------------------------------------------------------
__global__ __launch_bounds__(256) void k_glimpse(
    const float* __restrict__ refg, const float* __restrict__ qW,
    const float* __restrict__ vg, const float* __restrict__ enc,
    const int* __restrict__ unm, float* __restrict__ a,
    float* __restrict__ gl, int cnt)
{
    int b = blockIdx.x;
    int t = threadIdx.x, wave = t >> 6, lane = t & 63;
    __shared__ float ash[SS];
    __shared__ int sl[SS];
    if (t < cnt) sl[t] = unm[b * 64 + t];
    __syncthreads();
    int d0 = lane << 2;
    float4 qw = *(const float4*)(qW + (size_t)b * DD + d0);
    float4 vv = *(const float4*)(vg + d0);
    for (int li = wave; li < cnt; li += 4) {
        int s = sl[li];
        float4 r = *(const float4*)(refg + ((size_t)b * SS + s) * DD + d0);
        float sum = vv.x * tanhf(r.x + qw.x) + vv.y * tanhf(r.y + qw.y) +
                    vv.z * tanhf(r.z + qw.z) + vv.w * tanhf(r.w + qw.w);
#pragma unroll
        for (int off = 32; off; off >>= 1) sum += __shfl_xor(sum, off);
        if (lane == 0) ash[li] = sum;
    }
    __syncthreads();
    if (t < 64) {
        float logit = (t < cnt) ? ash[t] : -__builtin_inff();
        float m = logit;
#pragma unroll
        for (int off = 32; off; off >>= 1) m = fmaxf(m, __shfl_xor(m, off));
        float e = expf(logit - m);
        float ssum = e;
#pragma unroll
        for (int off = 32; off; off >>= 1) ssum += __shfl_xor(ssum, off);
        if (t < cnt) {
            float av = e / ssum;
            ash[t] = av;
            a[b * 64 + t] = av;
        }
    }
    __syncthreads();
    if (gl) {
        float accv = 0.0f;
        for (int li = 0; li < cnt; ++li)
            accv = fmaf(ash[li], enc[((size_t)sl[li] * BB + b) * DD + t], accv);
        gl[(size_t)b * DD + t] = accv;
    }
}

__global__ __launch_bounds__(256) void k_pointer(
    const float* __restrict__ refp, const float* __restrict__ refq,
    const float* __restrict__ gWin, const float* __restrict__ vp,
    const float* __restrict__ enc, int* __restrict__ unm,
    const float* __restrict__ a, float* __restrict__ lp,
    float* __restrict__ x, float* __restrict__ outp, int step, int cnt)
{
    int b = blockIdx.x;
    int t = threadIdx.x, wave = t >> 6, lane = t & 63;
    __shared__ float ash[SS];
    __shared__ int sl[SS];
    __shared__ float gw[DD];
    __shared__ int ssel;
    if (t < cnt) { sl[t] = unm[b * 64 + t]; ash[t] = a[b * 64 + t]; }
    __syncthreads();
    if (refq) {
        float accg = 0.0f;
        for (int li = 0; li < cnt; ++li)
            accg = fmaf(ash[li], refq[((size_t)b * SS + sl[li]) * DD + t], accg);
        gw[t] = accg;
    } else {
        gw[t] = gWin[(size_t)b * DD + t];
    }
    __syncthreads();
    int d0 = lane << 2;
    float4 g4 = *(const float4*)(gw + d0);
    float4 vv = *(const float4*)(vp + d0);
    for (int li = wave; li < cnt; li += 4) {
        int s = sl[li];
        float4 r = *(const float4*)(refp + ((size_t)b * SS + s) * DD + d0);
        float sum = vv.x * tanhf(r.x + g4.x) + vv.y * tanhf(r.y + g4.y) +
                    vv.z * tanhf(r.z + g4.z) + vv.w * tanhf(r.w + g4.w);
#pragma unroll
        for (int off = 32; off; off >>= 1) sum += __shfl_xor(sum, off);
        if (lane == 0) ash[li] = sum;
    }
    __syncthreads();
    if (t < 64) {
        float logit = (t < cnt) ? ash[t] : -__builtin_inff();
        int skey = (t < cnt) ? (sl[t] * 64 + t) : (1 << 30);
        float m = logit;
#pragma unroll
        for (int off = 32; off; off >>= 1) m = fmaxf(m, __shfl_xor(m, off));
        int cand = (logit == m) ? skey : (1 << 30);
#pragma unroll
        for (int off = 32; off; off >>= 1) cand = min(cand, __shfl_xor(cand, off));
        float e = expf(logit - m);
        float se = e;
#pragma unroll
        for (int off = 32; off; off >>= 1) se += __shfl_xor(se, off);
        if (t == 0) {
            int s_sel = cand >> 6, posl = cand & 63;
            float lpn = lp[b] - logf(se);
            lp[b] = lpn;
            outp[(size_t)b * STEPS + step] = (float)s_sel;
            if (step == STEPS - 1) outp[(size_t)BB * STEPS + b] = lpn;
            unm[b * 64 + posl] = sl[cnt - 1];
            ssel = s_sel;
        }
    }
    __syncthreads();
    x[(size_t)b * DD + t] = enc[((size_t)ssel * BB + b) * DD + t];
}

// ---------------------------------------------------------------------------
extern "C" void kernel_launch(void* const* d_in, const int* in_sizes, int n_in,
                              void* d_out, int out_size, void* d_ws, size_t ws_size,
                              hipStream_t stream) {
    const float* enc    = (const float*)d_in[0];
    const float* h0     = (const float*)d_in[1];
    const float* c0     = (const float*)d_in[2];
    const float* rk     = (const float*)d_in[3];
    const float* Wfirst = (const float*)d_in[4];
    const float* bfirst = (const float*)d_in[5];
    const float* Wih_f  = (const float*)d_in[6];
    const float* Whh_f  = (const float*)d_in[7];
    const float* bih_f  = (const float*)d_in[8];
    const float* bhh_f  = (const float*)d_in[9];
    const float* Wih_b  = (const float*)d_in[10];
    const float* Whh_b  = (const float*)d_in[11];
    const float* bih_b  = (const float*)d_in[12];
    const float* bhh_b  = (const float*)d_in[13];
    const float* Wref_g = (const float*)d_in[14];
    const float* Wq_g   = (const float*)d_in[15];
    const float* vg     = (const float*)d_in[16];
    const float* Wref   = (const float*)d_in[17];
    const float* Wq     = (const float*)d_in[18];
    const float* v      = (const float*)d_in[19];
    float* out = (float*)d_out;

    float* ws    = (float*)d_ws;
    float* refg  = ws;
    float* refp  = refg + NREF;
    float* x     = refp + NREF;
    float* q     = x + (size_t)BB * DD;
    float* c     = q + (size_t)BB * DD;
    float* gates = c + (size_t)2 * BB * HH;
    float* qWb   = gates + (size_t)BB * 1024;
    float* gl    = qWb + (size_t)BB * DD;
    float* gWb   = gl + (size_t)BB * DD;
    float* a     = gWb + (size_t)BB * DD;
    float* lp    = a + (size_t)BB * 64;
    int*   unm   = (int*)(lp + BB);
    float* refq  = (float*)(unm + (size_t)BB * 64);   // optional tail

    size_t need_refq = ((size_t)(refq - ws) + NREF) * sizeof(float);
    bool useRefq = ws_size >= need_refq;

    k_init<<<dim3(BB * DD / 256), dim3(256), 0, stream>>>(h0, c0, rk, Wfirst,
                                                          bfirst, x, q, c, unm, lp);
    k_refdot<<<dim3(BB * SS / 128, 1, useRefq ? 3 : 2), dim3(256), 0, stream>>>(
        enc, Wref_g, Wref, Wq, refg, refp, refq);
    for (int step = 0; step < STEPS; ++step) {
        int cnt = SS - step;
        k_gates<<<dim3(32, 8, 2), dim3(256), 0, stream>>>(
            x, q, Wih_f, Whh_f, bih_f, bhh_f, Wih_b, Whh_b, bih_b, bhh_b, gates);
        k_lstm_pw<<<dim3(2 * BB * HH / 256), dim3(256), 0, stream>>>(gates, q, c);
        k_proj<<<dim3(32, 4), dim3(256), 0, stream>>>(q, Wq_g, qWb);
        if (useRefq) {
            k_attn2<<<dim3(BB), dim3(256), 0, stream>>>(
                refg, refp, refq, qWb, vg, v, enc, unm, lp, x, out, step, cnt);
        } else {
            k_glimpse<<<dim3(BB), dim3(256), 0, stream>>>(refg, qWb, vg, enc, unm, a,
                                                          gl, cnt);
            k_proj<<<dim3(32, 4), dim3(256), 0, stream>>>(gl, Wq, gWb);
            k_pointer<<<dim3(BB), dim3(256), 0, stream>>>(refp, nullptr, gWb, v, enc,
                                                          unm, a, lp, x, out, step, cnt);
        }
    }
}